// Round 4
// baseline (933.907 us; speedup 1.0000x reference)
//
#include <hip/hip_runtime.h>
#include <cstdint>
#include <cstddef>

#define N_NODES 20000
#define N_EDGES 320000
#define NE_TOT  (N_EDGES + N_NODES)
#define BB 128
#define TT 200
#define EMB 128
#define GH 64
#define HEADS 4
#define LH 128
#define NSP 64
#define KF 136   // padded node-feature K (2 + 128 + 4 = 134 -> 136)

// ---------------------------------------------------------------- CSR build
__global__ void k_count(const int* __restrict__ ei, int* __restrict__ cnt) {
    int e = blockIdx.x * blockDim.x + threadIdx.x;
    if (e >= NE_TOT) return;
    int d = (e < N_EDGES) ? ei[N_EDGES + e] : (e - N_EDGES);
    atomicAdd(&cnt[d], 1);
}

__global__ __launch_bounds__(1024) void k_scan(const int* __restrict__ cnt, int* __restrict__ rs) {
    __shared__ int wsum[16];
    __shared__ int carry_s;
    int tid = threadIdx.x, lane = tid & 63, wv = tid >> 6;
    if (tid == 0) carry_s = 0;
    __syncthreads();
    for (int base = 0; base < N_NODES; base += 1024) {
        int v = (base + tid < N_NODES) ? cnt[base + tid] : 0;
        int x = v;
#pragma unroll
        for (int d = 1; d < 64; d <<= 1) {
            int t = __shfl_up(x, d, 64);
            if (lane >= d) x += t;
        }
        if (lane == 63) wsum[wv] = x;
        __syncthreads();
        if (wv == 0) {
            int s = (lane < 16) ? wsum[lane] : 0;
#pragma unroll
            for (int d = 1; d < 16; d <<= 1) {
                int t = __shfl_up(s, d, 64);
                if (lane >= d) s += t;
            }
            if (lane < 16) wsum[lane] = s;   // inclusive wave sums
        }
        __syncthreads();
        int woff = (wv > 0) ? wsum[wv - 1] : 0;
        int carry = carry_s;
        if (base + tid < N_NODES) rs[base + tid] = carry + woff + x - v;  // exclusive
        __syncthreads();
        if (tid == 0) carry_s = carry + wsum[15];
        __syncthreads();
    }
    if (threadIdx.x == 0) rs[N_NODES] = carry_s;
}

__global__ void k_scatter(const int* __restrict__ ei, int* __restrict__ cursor, int* __restrict__ csr) {
    int e = blockIdx.x * blockDim.x + threadIdx.x;
    if (e >= NE_TOT) return;
    int s, d;
    if (e < N_EDGES) { s = ei[e]; d = ei[N_EDGES + e]; }
    else             { s = d = e - N_EDGES; }
    int pos = atomicAdd(&cursor[d], 1);
    csr[pos] = s;
}

// ---------------------------------------------------------------- feature build
__global__ void k_build_nf(const float* __restrict__ xc, const float* __restrict__ tf,
                           const float* __restrict__ ne, float* __restrict__ nf) {
    int n = blockIdx.x, j = threadIdx.x;
    if (j >= KF) return;
    float v = 0.f;
    if (j < 2)        v = xc[n * 2 + j];
    else if (j < 130) v = ne[n * 128 + (j - 2)];
    else if (j < 134) v = tf[n * 4 + (j - 130)];
    nf[(size_t)n * KF + j] = v;
}

__global__ void k_build_w1p(const float* __restrict__ W, float* __restrict__ Wp) {
    int k = blockIdx.x, n = threadIdx.x;
    Wp[k * 256 + n] = (k < 134) ? W[k * 256 + n] : 0.f;
}

// combined W_ih^T for both directions -> WT[128][1024] = [wf^T | wb^T]; bc[1024] = [b_f | b_b]
__global__ void k_build_wih(const float* __restrict__ wf, const float* __restrict__ wb,
                            const float* __restrict__ bf, const float* __restrict__ bb,
                            float* __restrict__ WT, float* __restrict__ bc) {
    int idx = blockIdx.x * blockDim.x + threadIdx.x;
    if (idx < 512) bc[idx] = bf[idx];
    else if (idx < 1024) bc[idx] = bb[idx - 512];
    if (idx < 65536) {
        int g = idx & 511, k = idx >> 9;
        WT[k * 1024 + g] = wf[g * 128 + k];
    } else if (idx < 131072) {
        int i2 = idx - 65536;
        int g = i2 & 511, k = i2 >> 9;
        WT[k * 1024 + 512 + g] = wb[g * 128 + k];
    }
}

// ---------------------------------------------------------------- generic f32 GEMM
// C[M,N] = A[M,K] @ B[K,N] (+bias[n]); optional row gather on A.
// K % 8 == 0. BM=BN=128, BK=8, 256 threads, 8x8 micro-tile.
__global__ __launch_bounds__(256) void k_gemm_f32(
    const float* __restrict__ A, const float* __restrict__ B, float* __restrict__ C,
    int M, int N, int K, const int* __restrict__ gather, const float* __restrict__ bias)
{
    __shared__ float As[8][132];
    __shared__ float Bs[8][132];
    int tid = threadIdx.x;
    int bm = blockIdx.y << 7, bn = blockIdx.x << 7;
    int tm = ((tid >> 4) & 15) << 3;
    int tn = (tid & 15) << 3;
    float acc[8][8] = {};
    for (int k0 = 0; k0 < K; k0 += 8) {
        {
            int m = tid >> 1, kq = (tid & 1) << 2;
            int gm = bm + m;
            float4 v = make_float4(0.f, 0.f, 0.f, 0.f);
            if (gm < M) {
                int row = gather ? gather[gm] : gm;
                v = *(const float4*)(A + (size_t)row * K + k0 + kq);
            }
            As[kq + 0][m] = v.x; As[kq + 1][m] = v.y;
            As[kq + 2][m] = v.z; As[kq + 3][m] = v.w;
        }
        {
            int kk = tid >> 5, n4 = (tid & 31) << 2;
            int gn = bn + n4;
            float4 v = make_float4(0.f, 0.f, 0.f, 0.f);
            const float* brow = B + (size_t)(k0 + kk) * N;
            if (gn + 3 < N) v = *(const float4*)(brow + gn);
            else {
                if (gn + 0 < N) v.x = brow[gn + 0];
                if (gn + 1 < N) v.y = brow[gn + 1];
                if (gn + 2 < N) v.z = brow[gn + 2];
                if (gn + 3 < N) v.w = brow[gn + 3];
            }
            *(float4*)(&Bs[kk][n4]) = v;
        }
        __syncthreads();
#pragma unroll
        for (int k = 0; k < 8; k++) {
            float4 a0 = *(const float4*)&As[k][tm];
            float4 a1 = *(const float4*)&As[k][tm + 4];
            float4 b0 = *(const float4*)&Bs[k][tn];
            float4 b1 = *(const float4*)&Bs[k][tn + 4];
            float av[8] = {a0.x, a0.y, a0.z, a0.w, a1.x, a1.y, a1.z, a1.w};
            float bv[8] = {b0.x, b0.y, b0.z, b0.w, b1.x, b1.y, b1.z, b1.w};
#pragma unroll
            for (int i = 0; i < 8; i++)
#pragma unroll
                for (int j = 0; j < 8; j++)
                    acc[i][j] = fmaf(av[i], bv[j], acc[i][j]);
        }
        __syncthreads();
    }
#pragma unroll
    for (int i = 0; i < 8; i++) {
        int gm = bm + tm + i;
        if (gm >= M) continue;
        float* crow = C + (size_t)gm * N;
#pragma unroll
        for (int j4 = 0; j4 < 8; j4 += 4) {
            int gn = bn + tn + j4;
            if (gn + 3 < N) {
                float4 v = make_float4(acc[i][j4], acc[i][j4 + 1], acc[i][j4 + 2], acc[i][j4 + 3]);
                if (bias) { v.x += bias[gn]; v.y += bias[gn + 1]; v.z += bias[gn + 2]; v.w += bias[gn + 3]; }
                *(float4*)(crow + gn) = v;
            } else {
#pragma unroll
                for (int j = 0; j < 4; j++) {
                    int g2 = gn + j;
                    if (g2 < N) crow[g2] = acc[i][j4 + j] + (bias ? bias[g2] : 0.f);
                }
            }
        }
    }
}

// ---------------------------------------------------------------- GAT attention dots
template <int H, int C>
__global__ void k_attn_dots(const float* __restrict__ hm, const float* __restrict__ asrc,
                            const float* __restrict__ adst, float* __restrict__ a_s,
                            float* __restrict__ a_d) {
    int wave = (blockIdx.x * blockDim.x + threadIdx.x) >> 6;
    int lane = threadIdx.x & 63;
    if (wave >= N_NODES * H) return;
    int n = wave / H, h = wave - n * H;
    const float* row = hm + (size_t)n * (H * C) + h * C;
    float ps = 0.f, pd = 0.f;
#pragma unroll
    for (int c0 = 0; c0 < C; c0 += 64) {
        float v = row[c0 + lane];
        ps += v * asrc[h * C + c0 + lane];
        pd += v * adst[h * C + c0 + lane];
    }
#pragma unroll
    for (int off = 32; off > 0; off >>= 1) {
        ps += __shfl_down(ps, off);
        pd += __shfl_down(pd, off);
    }
    if (lane == 0) { a_s[wave] = ps; a_d[wave] = pd; }
}

// ---------------------------------------------------------------- GAT segment softmax + aggregate
template <int H, int C, bool DO_ELU>
__global__ void k_gat_aggregate(const float* __restrict__ hm, const float* __restrict__ a_s,
                                const float* __restrict__ a_d, const int* __restrict__ rs,
                                const int* __restrict__ csr, const float* __restrict__ bias,
                                float* __restrict__ out) {
    int d = blockIdx.x;
    int tid = threadIdx.x;
    int h = tid / C;
    int r0 = rs[d], r1 = rs[d + 1];
    float adv = a_d[d * H + h];
    float m = -1e30f;
    for (int j = r0; j < r1; j++) {
        int s = csr[j];
        float e = a_s[s * H + h] + adv;
        e = (e > 0.f) ? e : 0.2f * e;
        m = fmaxf(m, e);
    }
    float den = 0.f, acc = 0.f;
    for (int j = r0; j < r1; j++) {
        int s = csr[j];
        float e = a_s[s * H + h] + adv;
        e = (e > 0.f) ? e : 0.2f * e;
        float ex = __expf(e - m);
        den += ex;
        acc += ex * hm[(size_t)s * (H * C) + tid];
    }
    float r = acc / den + bias[tid];
    if (DO_ELU) r = (r > 0.f) ? r : expm1f(r);
    out[(size_t)d * (H * C) + tid] = r;
}

// ---------------------------------------------------------------- BiLSTM recurrence
__device__ __forceinline__ float sigmf(float x) { return 1.f / (1.f + __expf(-x)); }
__device__ __forceinline__ float tanhfast(float x) {
    x = fminf(fmaxf(x, -20.f), 20.f);
    float e = __expf(2.f * x);
    return (e - 1.f) / (e + 1.f);
}
__device__ __forceinline__ float bcast(float v, int l) {
    return __uint_as_float(__builtin_amdgcn_readlane(__float_as_uint(v), l));
}

// one block per (batch, direction); 1024 threads; thread (g = tid&511, hf = tid>>9)
// owns W_hh[g][hf*64 .. hf*64+63] as 16 NAMED float4 SSA values — a C array here
// is left as a scratch alloca by the AMDGPU promote-alloca pass (R2: VGPR=76,
// R3: VGPR=44 with 13 GB/launch scratch reload traffic); named values force VGPRs.
__global__ __launch_bounds__(1024, 4) void k_lstm(
    const float* __restrict__ xg,      // [B*T][1024] = f-gates | b-gates
    const float* __restrict__ whh_f, const float* __restrict__ whh_b,
    const int* __restrict__ lengths, float* __restrict__ lstm_out)
{
    int b = blockIdx.x & 127;
    int dir = blockIdx.x >> 7;
    int tid = threadIdx.x;
    int g = tid & 511;
    int hf = tid >> 9;           // wave-uniform (waves 0-7: hf=0, 8-15: hf=1)
    int lane = tid & 63;
    const float* whh = dir ? whh_b : whh_f;
    int L = lengths[b];

    const float4* wrow = (const float4*)(whh + (size_t)g * LH + hf * 64);
    float4 W0  = wrow[0],  W1  = wrow[1],  W2  = wrow[2],  W3  = wrow[3];
    float4 W4  = wrow[4],  W5  = wrow[5],  W6  = wrow[6],  W7  = wrow[7];
    float4 W8  = wrow[8],  W9  = wrow[9],  W10 = wrow[10], W11 = wrow[11];
    float4 W12 = wrow[12], W13 = wrow[13], W14 = wrow[14], W15 = wrow[15];

    __shared__ float hbuf[LH];
    __shared__ float gpart[1024];
    if (tid < LH) hbuf[tid] = 0.f;
    float c = 0.f;
    int tx0 = dir ? (L - 1) : 0;
    float xg_cur = (hf == 0) ? xg[((size_t)b * TT + tx0) * 1024 + dir * 512 + g] : 0.f;
    __syncthreads();

    for (int t = 0; t < L; t++) {
        int tx = dir ? (L - 1 - t) : t;
        float hv0 = hbuf[hf * 64 + lane];          // readlane(hv0,l) = h[hf*64+l]
        float xg_nxt = 0.f;
        if (hf == 0 && t + 1 < L) {
            int txn = dir ? (L - 2 - t) : (t + 1);
            xg_nxt = xg[((size_t)b * TT + txn) * 1024 + dir * 512 + g];
        }
        float a0 = xg_cur, a1 = 0.f, a2 = 0.f, a3 = 0.f;
#define ACC4(W, B) \
        a0 = fmaf(W.x, bcast(hv0, (B) + 0), a0); \
        a1 = fmaf(W.y, bcast(hv0, (B) + 1), a1); \
        a2 = fmaf(W.z, bcast(hv0, (B) + 2), a2); \
        a3 = fmaf(W.w, bcast(hv0, (B) + 3), a3);
        ACC4(W0, 0)   ACC4(W1, 4)   ACC4(W2, 8)   ACC4(W3, 12)
        ACC4(W4, 16)  ACC4(W5, 20)  ACC4(W6, 24)  ACC4(W7, 28)
        ACC4(W8, 32)  ACC4(W9, 36)  ACC4(W10, 40) ACC4(W11, 44)
        ACC4(W12, 48) ACC4(W13, 52) ACC4(W14, 56) ACC4(W15, 60)
#undef ACC4
        gpart[tid] = (a0 + a1) + (a2 + a3);
        __syncthreads();
        if (tid < LH) {
            float pi = gpart[tid]       + gpart[512 + tid];
            float pf = gpart[128 + tid] + gpart[640 + tid];
            float pg = gpart[256 + tid] + gpart[768 + tid];
            float po = gpart[384 + tid] + gpart[896 + tid];
            float ig = sigmf(pi);
            float fg = sigmf(pf);
            float gg = tanhfast(pg);
            float og = sigmf(po);
            c = fg * c + ig * gg;
            float hv = og * tanhfast(c);
            hbuf[tid] = hv;
            lstm_out[((size_t)b * TT + tx) * (2 * LH) + dir * LH + tid] = hv;
        }
        xg_cur = xg_nxt;
        __syncthreads();
    }
}

// ---------------------------------------------------------------- masked attention pooling (both pools fused)
__global__ __launch_bounds__(256) void k_attnpool(
    const float* __restrict__ lo, const int* __restrict__ lengths,
    const float* __restrict__ wn, const float* __restrict__ bn,
    const float* __restrict__ wsp, const float* __restrict__ bsp,
    float* __restrict__ ctxn, float* __restrict__ ctxs)
{
    int b = blockIdx.x;
    int tid = threadIdx.x;
    int L = lengths[b];
    __shared__ float sn[TT], ss[TT];
    __shared__ float red[256];
    int wv = tid >> 6, lane = tid & 63;
    for (int t = wv; t < L; t += 4) {
        const float* row = lo + ((size_t)b * TT + t) * (2 * LH);
        float pn = 0.f, ps = 0.f;
#pragma unroll
        for (int c0 = 0; c0 < 256; c0 += 64) {
            float v = row[c0 + lane];
            pn += v * wn[c0 + lane];
            ps += v * wsp[c0 + lane];
        }
#pragma unroll
        for (int off = 32; off > 0; off >>= 1) {
            pn += __shfl_down(pn, off);
            ps += __shfl_down(ps, off);
        }
        if (lane == 0) { sn[t] = pn + bn[0]; ss[t] = ps + bsp[0]; }
    }
    __syncthreads();
    float vn = (tid < L) ? sn[tid] : -1e30f;
    float vs = (tid < L) ? ss[tid] : -1e30f;
    red[tid] = vn; __syncthreads();
    for (int s = 128; s > 0; s >>= 1) { if (tid < s) red[tid] = fmaxf(red[tid], red[tid + s]); __syncthreads(); }
    float mn = red[0]; __syncthreads();
    red[tid] = vs; __syncthreads();
    for (int s = 128; s > 0; s >>= 1) { if (tid < s) red[tid] = fmaxf(red[tid], red[tid + s]); __syncthreads(); }
    float ms = red[0]; __syncthreads();
    float en = (tid < L) ? __expf(vn - mn) : 0.f;
    float es = (tid < L) ? __expf(vs - ms) : 0.f;
    red[tid] = en; __syncthreads();
    for (int s = 128; s > 0; s >>= 1) { if (tid < s) red[tid] += red[tid + s]; __syncthreads(); }
    float dn = red[0]; __syncthreads();
    red[tid] = es; __syncthreads();
    for (int s = 128; s > 0; s >>= 1) { if (tid < s) red[tid] += red[tid + s]; __syncthreads(); }
    float dsum = red[0]; __syncthreads();
    if (tid < L) { sn[tid] = en / dn; ss[tid] = es / dsum; }
    __syncthreads();
    float an = 0.f, asv = 0.f;
    for (int t = 0; t < L; t++) {
        float v = lo[((size_t)b * TT + t) * (2 * LH) + tid];
        an += sn[t] * v;
        asv += ss[t] * v;
    }
    ctxn[b * (2 * LH) + tid] = an;
    ctxs[b * (2 * LH) + tid] = asv;
}

// ---------------------------------------------------------------- launch
extern "C" void kernel_launch(void* const* d_in, const int* in_sizes, int n_in,
                              void* d_out, int out_size, void* d_ws, size_t ws_size,
                              hipStream_t stream) {
    (void)in_sizes; (void)n_in; (void)out_size; (void)ws_size;
    const float* x_coords = (const float*)d_in[0];
    const float* temporal = (const float*)d_in[1];
    const float* node_emb = (const float*)d_in[2];
    const float* gat1_W   = (const float*)d_in[3];
    const float* gat1_as  = (const float*)d_in[4];
    const float* gat1_ad  = (const float*)d_in[5];
    const float* gat1_b   = (const float*)d_in[6];
    const float* gat2_W   = (const float*)d_in[7];
    const float* gat2_as  = (const float*)d_in[8];
    const float* gat2_ad  = (const float*)d_in[9];
    const float* gat2_b   = (const float*)d_in[10];
    const float* w_ih_f   = (const float*)d_in[11];
    const float* w_hh_f   = (const float*)d_in[12];
    const float* b_f      = (const float*)d_in[13];
    const float* w_ih_b   = (const float*)d_in[14];
    const float* w_hh_b   = (const float*)d_in[15];
    const float* b_b      = (const float*)d_in[16];
    const float* attn_n_w = (const float*)d_in[17];
    const float* attn_n_b = (const float*)d_in[18];
    const float* attn_s_w = (const float*)d_in[19];
    const float* attn_s_b = (const float*)d_in[20];
    const float* fc_n_W   = (const float*)d_in[21];
    const float* fc_n_b   = (const float*)d_in[22];
    const float* fc_s_W   = (const float*)d_in[23];
    const float* fc_s_b   = (const float*)d_in[24];
    const int*   edge_idx = (const int*)d_in[25];
    const int*   seq      = (const int*)d_in[26];
    const int*   lengths  = (const int*)d_in[27];

    char* ws = (char*)d_ws;
    size_t off = 0;
    auto alloc = [&](size_t bytes) -> char* {
        char* p = ws + off;
        off += (bytes + 255) & ~(size_t)255;
        return p;
    };
    int*   cnt      = (int*)alloc((size_t)N_NODES * 4);
    int*   rowstart = (int*)alloc((size_t)(N_NODES + 1) * 4);
    int*   cursor   = (int*)alloc((size_t)N_NODES * 4);
    int*   csr      = (int*)alloc((size_t)NE_TOT * 4);
    float* z2       = (float*)alloc((size_t)N_NODES * EMB * 4);
    float* lstm_o   = (float*)alloc((size_t)BB * TT * 2 * LH * 4);
    float* ctxn     = (float*)alloc((size_t)BB * 2 * LH * 4);
    float* ctxs     = (float*)alloc((size_t)BB * 2 * LH * 4);
    float* wT       = (float*)alloc((size_t)128 * 1024 * 4);
    float* bc       = (float*)alloc((size_t)1024 * 4);
    // reused region: GAT scratch first, then xg buffer (GAT scratch dead by then)
    float* nf  = (float*)(ws + off);
    float* w1p = nf + (size_t)N_NODES * KF;
    float* h1  = w1p + (size_t)KF * 256;
    float* as1 = h1 + (size_t)N_NODES * 256;
    float* ad1 = as1 + (size_t)N_NODES * 4;
    float* z1  = ad1 + (size_t)N_NODES * 4;
    float* h2  = z1 + (size_t)N_NODES * 256;
    float* as2 = h2 + (size_t)N_NODES * 128;
    float* ad2 = as2 + (size_t)N_NODES;
    float* xgc = (float*)(ws + off);               // [25600][1024], overlays nf..ad2

    // --- CSR build
    hipMemsetAsync(cnt, 0, (size_t)N_NODES * 4, stream);
    k_count<<<(NE_TOT + 255) / 256, 256, 0, stream>>>(edge_idx, cnt);
    k_scan<<<1, 1024, 0, stream>>>(cnt, rowstart);
    hipMemcpyAsync(cursor, rowstart, (size_t)N_NODES * 4, hipMemcpyDeviceToDevice, stream);
    k_scatter<<<(NE_TOT + 255) / 256, 256, 0, stream>>>(edge_idx, cursor, csr);

    // --- GAT layer 1
    k_build_nf<<<N_NODES, 192, 0, stream>>>(x_coords, temporal, node_emb, nf);
    k_build_w1p<<<KF, 256, 0, stream>>>(gat1_W, w1p);
    {
        dim3 g(2, (N_NODES + 127) / 128);
        k_gemm_f32<<<g, 256, 0, stream>>>(nf, w1p, h1, N_NODES, 256, KF, nullptr, nullptr);
    }
    k_attn_dots<HEADS, GH><<<(N_NODES * HEADS + 3) / 4, 256, 0, stream>>>(h1, gat1_as, gat1_ad, as1, ad1);
    k_gat_aggregate<HEADS, GH, true><<<N_NODES, 256, 0, stream>>>(h1, as1, ad1, rowstart, csr, gat1_b, z1);

    // --- GAT layer 2
    {
        dim3 g(1, (N_NODES + 127) / 128);
        k_gemm_f32<<<g, 256, 0, stream>>>(z1, gat2_W, h2, N_NODES, 128, 256, nullptr, nullptr);
    }
    k_attn_dots<1, EMB><<<(N_NODES + 3) / 4, 256, 0, stream>>>(h2, gat2_as, gat2_ad, as2, ad2);
    k_gat_aggregate<1, EMB, false><<<N_NODES, 128, 0, stream>>>(h2, as2, ad2, rowstart, csr, gat2_b, z2);

    // --- x-gate precompute, both directions in one GEMM (gather z2[seq] fused)
    k_build_wih<<<512, 256, 0, stream>>>(w_ih_f, w_ih_b, b_f, b_b, wT, bc);
    {
        dim3 g(8, (BB * TT) / 128);
        k_gemm_f32<<<g, 256, 0, stream>>>(z2, wT, xgc, BB * TT, 1024, 128, seq, bc);
    }

    // --- BiLSTM recurrence (W_hh as named SSA float4s -> forced register residency)
    k_lstm<<<256, 1024, 0, stream>>>(xgc, w_hh_f, w_hh_b, lengths, lstm_o);

    // --- attention pooling
    k_attnpool<<<BB, 256, 0, stream>>>(lstm_o, lengths, attn_n_w, attn_n_b, attn_s_w, attn_s_b, ctxn, ctxs);

    // --- output heads
    float* out_node = (float*)d_out;
    float* out_sp   = out_node + (size_t)BB * N_NODES;
    {
        dim3 g((N_NODES + 127) / 128, 1);
        k_gemm_f32<<<g, 256, 0, stream>>>(ctxn, fc_n_W, out_node, BB, N_NODES, 256, nullptr, fc_n_b);
    }
    {
        dim3 g(1, 1);
        k_gemm_f32<<<g, 256, 0, stream>>>(ctxs, fc_s_W, out_sp, BB, NSP, 256, nullptr, fc_s_b);
    }
}

// Round 6
// 916.444 us; speedup vs baseline: 1.0191x; 1.0191x over previous
//
#include <hip/hip_runtime.h>
#include <cstdint>
#include <cstddef>

#define N_NODES 20000
#define N_EDGES 320000
#define NE_TOT  (N_EDGES + N_NODES)
#define BB 128
#define TT 200
#define EMB 128
#define GH 64
#define HEADS 4
#define LH 128
#define NSP 64
#define KF 136   // padded node-feature K (2 + 128 + 4 = 134 -> 136)

// ---------------------------------------------------------------- CSR build
__global__ void k_count(const int* __restrict__ ei, int* __restrict__ cnt) {
    int e = blockIdx.x * blockDim.x + threadIdx.x;
    if (e >= NE_TOT) return;
    int d = (e < N_EDGES) ? ei[N_EDGES + e] : (e - N_EDGES);
    atomicAdd(&cnt[d], 1);
}

__global__ __launch_bounds__(1024) void k_scan(const int* __restrict__ cnt, int* __restrict__ rs) {
    __shared__ int wsum[16];
    __shared__ int carry_s;
    int tid = threadIdx.x, lane = tid & 63, wv = tid >> 6;
    if (tid == 0) carry_s = 0;
    __syncthreads();
    for (int base = 0; base < N_NODES; base += 1024) {
        int v = (base + tid < N_NODES) ? cnt[base + tid] : 0;
        int x = v;
#pragma unroll
        for (int d = 1; d < 64; d <<= 1) {
            int t = __shfl_up(x, d, 64);
            if (lane >= d) x += t;
        }
        if (lane == 63) wsum[wv] = x;
        __syncthreads();
        if (wv == 0) {
            int s = (lane < 16) ? wsum[lane] : 0;
#pragma unroll
            for (int d = 1; d < 16; d <<= 1) {
                int t = __shfl_up(s, d, 64);
                if (lane >= d) s += t;
            }
            if (lane < 16) wsum[lane] = s;   // inclusive wave sums
        }
        __syncthreads();
        int woff = (wv > 0) ? wsum[wv - 1] : 0;
        int carry = carry_s;
        if (base + tid < N_NODES) rs[base + tid] = carry + woff + x - v;  // exclusive
        __syncthreads();
        if (tid == 0) carry_s = carry + wsum[15];
        __syncthreads();
    }
    if (threadIdx.x == 0) rs[N_NODES] = carry_s;
}

__global__ void k_scatter(const int* __restrict__ ei, int* __restrict__ cursor, int* __restrict__ csr) {
    int e = blockIdx.x * blockDim.x + threadIdx.x;
    if (e >= NE_TOT) return;
    int s, d;
    if (e < N_EDGES) { s = ei[e]; d = ei[N_EDGES + e]; }
    else             { s = d = e - N_EDGES; }
    int pos = atomicAdd(&cursor[d], 1);
    csr[pos] = s;
}

// ---------------------------------------------------------------- feature build
__global__ void k_build_nf(const float* __restrict__ xc, const float* __restrict__ tf,
                           const float* __restrict__ ne, float* __restrict__ nf) {
    int n = blockIdx.x, j = threadIdx.x;
    if (j >= KF) return;
    float v = 0.f;
    if (j < 2)        v = xc[n * 2 + j];
    else if (j < 130) v = ne[n * 128 + (j - 2)];
    else if (j < 134) v = tf[n * 4 + (j - 130)];
    nf[(size_t)n * KF + j] = v;
}

__global__ void k_build_w1p(const float* __restrict__ W, float* __restrict__ Wp) {
    int k = blockIdx.x, n = threadIdx.x;
    Wp[k * 256 + n] = (k < 134) ? W[k * 256 + n] : 0.f;
}

// combined W_ih^T for both directions -> WT[128][1024] = [wf^T | wb^T]; bc[1024] = [b_f | b_b]
__global__ void k_build_wih(const float* __restrict__ wf, const float* __restrict__ wb,
                            const float* __restrict__ bf, const float* __restrict__ bb,
                            float* __restrict__ WT, float* __restrict__ bc) {
    int idx = blockIdx.x * blockDim.x + threadIdx.x;
    if (idx < 512) bc[idx] = bf[idx];
    else if (idx < 1024) bc[idx] = bb[idx - 512];
    if (idx < 65536) {
        int g = idx & 511, k = idx >> 9;
        WT[k * 1024 + g] = wf[g * 128 + k];
    } else if (idx < 131072) {
        int i2 = idx - 65536;
        int g = i2 & 511, k = i2 >> 9;
        WT[k * 1024 + 512 + g] = wb[g * 128 + k];
    }
}

// ---------------------------------------------------------------- generic f32 GEMM
// C[M,N] = A[M,K] @ B[K,N] (+bias[n]); optional row gather on A.
// K % 8 == 0. BM=BN=128, BK=8, 256 threads, 8x8 micro-tile.
__global__ __launch_bounds__(256) void k_gemm_f32(
    const float* __restrict__ A, const float* __restrict__ B, float* __restrict__ C,
    int M, int N, int K, const int* __restrict__ gather, const float* __restrict__ bias)
{
    __shared__ float As[8][132];
    __shared__ float Bs[8][132];
    int tid = threadIdx.x;
    int bm = blockIdx.y << 7, bn = blockIdx.x << 7;
    int tm = ((tid >> 4) & 15) << 3;
    int tn = (tid & 15) << 3;
    float acc[8][8] = {};
    for (int k0 = 0; k0 < K; k0 += 8) {
        {
            int m = tid >> 1, kq = (tid & 1) << 2;
            int gm = bm + m;
            float4 v = make_float4(0.f, 0.f, 0.f, 0.f);
            if (gm < M) {
                int row = gather ? gather[gm] : gm;
                v = *(const float4*)(A + (size_t)row * K + k0 + kq);
            }
            As[kq + 0][m] = v.x; As[kq + 1][m] = v.y;
            As[kq + 2][m] = v.z; As[kq + 3][m] = v.w;
        }
        {
            int kk = tid >> 5, n4 = (tid & 31) << 2;
            int gn = bn + n4;
            float4 v = make_float4(0.f, 0.f, 0.f, 0.f);
            const float* brow = B + (size_t)(k0 + kk) * N;
            if (gn + 3 < N) v = *(const float4*)(brow + gn);
            else {
                if (gn + 0 < N) v.x = brow[gn + 0];
                if (gn + 1 < N) v.y = brow[gn + 1];
                if (gn + 2 < N) v.z = brow[gn + 2];
                if (gn + 3 < N) v.w = brow[gn + 3];
            }
            *(float4*)(&Bs[kk][n4]) = v;
        }
        __syncthreads();
#pragma unroll
        for (int k = 0; k < 8; k++) {
            float4 a0 = *(const float4*)&As[k][tm];
            float4 a1 = *(const float4*)&As[k][tm + 4];
            float4 b0 = *(const float4*)&Bs[k][tn];
            float4 b1 = *(const float4*)&Bs[k][tn + 4];
            float av[8] = {a0.x, a0.y, a0.z, a0.w, a1.x, a1.y, a1.z, a1.w};
            float bv[8] = {b0.x, b0.y, b0.z, b0.w, b1.x, b1.y, b1.z, b1.w};
#pragma unroll
            for (int i = 0; i < 8; i++)
#pragma unroll
                for (int j = 0; j < 8; j++)
                    acc[i][j] = fmaf(av[i], bv[j], acc[i][j]);
        }
        __syncthreads();
    }
#pragma unroll
    for (int i = 0; i < 8; i++) {
        int gm = bm + tm + i;
        if (gm >= M) continue;
        float* crow = C + (size_t)gm * N;
#pragma unroll
        for (int j4 = 0; j4 < 8; j4 += 4) {
            int gn = bn + tn + j4;
            if (gn + 3 < N) {
                float4 v = make_float4(acc[i][j4], acc[i][j4 + 1], acc[i][j4 + 2], acc[i][j4 + 3]);
                if (bias) { v.x += bias[gn]; v.y += bias[gn + 1]; v.z += bias[gn + 2]; v.w += bias[gn + 3]; }
                *(float4*)(crow + gn) = v;
            } else {
#pragma unroll
                for (int j = 0; j < 4; j++) {
                    int g2 = gn + j;
                    if (g2 < N) crow[g2] = acc[i][j4 + j] + (bias ? bias[g2] : 0.f);
                }
            }
        }
    }
}

// ---------------------------------------------------------------- GAT attention dots
template <int H, int C>
__global__ void k_attn_dots(const float* __restrict__ hm, const float* __restrict__ asrc,
                            const float* __restrict__ adst, float* __restrict__ a_s,
                            float* __restrict__ a_d) {
    int wave = (blockIdx.x * blockDim.x + threadIdx.x) >> 6;
    int lane = threadIdx.x & 63;
    if (wave >= N_NODES * H) return;
    int n = wave / H, h = wave - n * H;
    const float* row = hm + (size_t)n * (H * C) + h * C;
    float ps = 0.f, pd = 0.f;
#pragma unroll
    for (int c0 = 0; c0 < C; c0 += 64) {
        float v = row[c0 + lane];
        ps += v * asrc[h * C + c0 + lane];
        pd += v * adst[h * C + c0 + lane];
    }
#pragma unroll
    for (int off = 32; off > 0; off >>= 1) {
        ps += __shfl_down(ps, off);
        pd += __shfl_down(pd, off);
    }
    if (lane == 0) { a_s[wave] = ps; a_d[wave] = pd; }
}

// ---------------------------------------------------------------- GAT segment softmax + aggregate
template <int H, int C, bool DO_ELU>
__global__ void k_gat_aggregate(const float* __restrict__ hm, const float* __restrict__ a_s,
                                const float* __restrict__ a_d, const int* __restrict__ rs,
                                const int* __restrict__ csr, const float* __restrict__ bias,
                                float* __restrict__ out) {
    int d = blockIdx.x;
    int tid = threadIdx.x;
    int h = tid / C;
    int r0 = rs[d], r1 = rs[d + 1];
    float adv = a_d[d * H + h];
    float m = -1e30f;
    for (int j = r0; j < r1; j++) {
        int s = csr[j];
        float e = a_s[s * H + h] + adv;
        e = (e > 0.f) ? e : 0.2f * e;
        m = fmaxf(m, e);
    }
    float den = 0.f, acc = 0.f;
    for (int j = r0; j < r1; j++) {
        int s = csr[j];
        float e = a_s[s * H + h] + adv;
        e = (e > 0.f) ? e : 0.2f * e;
        float ex = __expf(e - m);
        den += ex;
        acc += ex * hm[(size_t)s * (H * C) + tid];
    }
    float r = acc / den + bias[tid];
    if (DO_ELU) r = (r > 0.f) ? r : expm1f(r);
    out[(size_t)d * (H * C) + tid] = r;
}

// ---------------------------------------------------------------- BiLSTM recurrence
__device__ __forceinline__ float sigmf(float x) { return 1.f / (1.f + __expf(-x)); }
__device__ __forceinline__ float tanhfast(float x) {
    x = fminf(fmaxf(x, -20.f), 20.f);
    float e = __expf(2.f * x);
    return (e - 1.f) / (e + 1.f);
}
__device__ __forceinline__ float bcast(float v, int l) {
    return __uint_as_float(__builtin_amdgcn_readlane(__float_as_uint(v), l));
}

// one block per (batch, direction); 1024 threads; thread (g = tid&511, hf = tid>>9)
// owns W_hh[g][hf*64 .. hf*64+63]. R1-R4 lesson (VGPR=88/76/44/44, dur ~240us all):
// any W load the compiler can SEE gets rematerialized into the loop by the
// occupancy-targeting scheduler -> W streams from L1/L2 every step. One opaque asm
// block (16 loads + waitcnt, early-clobber outputs) forces true VGPR residency:
// asm outputs cannot be rematerialized and only become live after the waitcnt.
__global__ __launch_bounds__(1024, 4) void k_lstm(
    const float* __restrict__ xg,      // [B*T][1024] = f-gates | b-gates
    const float* __restrict__ whh_f, const float* __restrict__ whh_b,
    const int* __restrict__ lengths, float* __restrict__ lstm_out)
{
    int b = blockIdx.x & 127;
    int dir = blockIdx.x >> 7;
    int tid = threadIdx.x;
    int g = tid & 511;
    int hf = tid >> 9;           // wave-uniform (waves 0-7: hf=0, 8-15: hf=1)
    int lane = tid & 63;
    const float* whh = dir ? whh_b : whh_f;
    int L = lengths[b];

    const float* wp = whh + (size_t)g * LH + hf * 64;
    float4 W0, W1, W2, W3, W4, W5, W6, W7, W8, W9, W10, W11, W12, W13, W14, W15;
    asm volatile(
        "global_load_dwordx4 %0,  %16, off offset:0\n\t"
        "global_load_dwordx4 %1,  %16, off offset:16\n\t"
        "global_load_dwordx4 %2,  %16, off offset:32\n\t"
        "global_load_dwordx4 %3,  %16, off offset:48\n\t"
        "global_load_dwordx4 %4,  %16, off offset:64\n\t"
        "global_load_dwordx4 %5,  %16, off offset:80\n\t"
        "global_load_dwordx4 %6,  %16, off offset:96\n\t"
        "global_load_dwordx4 %7,  %16, off offset:112\n\t"
        "global_load_dwordx4 %8,  %16, off offset:128\n\t"
        "global_load_dwordx4 %9,  %16, off offset:144\n\t"
        "global_load_dwordx4 %10, %16, off offset:160\n\t"
        "global_load_dwordx4 %11, %16, off offset:176\n\t"
        "global_load_dwordx4 %12, %16, off offset:192\n\t"
        "global_load_dwordx4 %13, %16, off offset:208\n\t"
        "global_load_dwordx4 %14, %16, off offset:224\n\t"
        "global_load_dwordx4 %15, %16, off offset:240\n\t"
        "s_waitcnt vmcnt(0)"
        : "=&v"(W0), "=&v"(W1), "=&v"(W2),  "=&v"(W3),
          "=&v"(W4), "=&v"(W5), "=&v"(W6),  "=&v"(W7),
          "=&v"(W8), "=&v"(W9), "=&v"(W10), "=&v"(W11),
          "=&v"(W12), "=&v"(W13), "=&v"(W14), "=&v"(W15)
        : "v"(wp));

    __shared__ float hbuf[LH];
    __shared__ float gpart[1024];
    if (tid < LH) hbuf[tid] = 0.f;
    float c = 0.f;
    int tx0 = dir ? (L - 1) : 0;
    float xg_cur = (hf == 0) ? xg[((size_t)b * TT + tx0) * 1024 + dir * 512 + g] : 0.f;
    __syncthreads();

    for (int t = 0; t < L; t++) {
        int tx = dir ? (L - 1 - t) : t;
        float hv0 = hbuf[hf * 64 + lane];          // readlane(hv0,l) = h[hf*64+l]
        float xg_nxt = 0.f;
        if (hf == 0 && t + 1 < L) {
            int txn = dir ? (L - 2 - t) : (t + 1);
            xg_nxt = xg[((size_t)b * TT + txn) * 1024 + dir * 512 + g];
        }
        float a0 = xg_cur, a1 = 0.f, a2 = 0.f, a3 = 0.f;
#define ACC4(W, B) \
        a0 = fmaf(W.x, bcast(hv0, (B) + 0), a0); \
        a1 = fmaf(W.y, bcast(hv0, (B) + 1), a1); \
        a2 = fmaf(W.z, bcast(hv0, (B) + 2), a2); \
        a3 = fmaf(W.w, bcast(hv0, (B) + 3), a3);
        ACC4(W0, 0)   ACC4(W1, 4)   ACC4(W2, 8)   ACC4(W3, 12)
        ACC4(W4, 16)  ACC4(W5, 20)  ACC4(W6, 24)  ACC4(W7, 28)
        ACC4(W8, 32)  ACC4(W9, 36)  ACC4(W10, 40) ACC4(W11, 44)
        ACC4(W12, 48) ACC4(W13, 52) ACC4(W14, 56) ACC4(W15, 60)
#undef ACC4
        gpart[tid] = (a0 + a1) + (a2 + a3);
        __syncthreads();
        if (tid < LH) {
            float pi = gpart[tid]       + gpart[512 + tid];
            float pf = gpart[128 + tid] + gpart[640 + tid];
            float pg = gpart[256 + tid] + gpart[768 + tid];
            float po = gpart[384 + tid] + gpart[896 + tid];
            float ig = sigmf(pi);
            float fg = sigmf(pf);
            float gg = tanhfast(pg);
            float og = sigmf(po);
            c = fg * c + ig * gg;
            float hv = og * tanhfast(c);
            hbuf[tid] = hv;
            lstm_out[((size_t)b * TT + tx) * (2 * LH) + dir * LH + tid] = hv;
        }
        xg_cur = xg_nxt;
        __syncthreads();
    }
}

// ---------------------------------------------------------------- masked attention pooling (both pools fused)
__global__ __launch_bounds__(256) void k_attnpool(
    const float* __restrict__ lo, const int* __restrict__ lengths,
    const float* __restrict__ wn, const float* __restrict__ bn,
    const float* __restrict__ wsp, const float* __restrict__ bsp,
    float* __restrict__ ctxn, float* __restrict__ ctxs)
{
    int b = blockIdx.x;
    int tid = threadIdx.x;
    int L = lengths[b];
    __shared__ float sn[TT], ss[TT];
    __shared__ float red[256];
    int wv = tid >> 6, lane = tid & 63;
    for (int t = wv; t < L; t += 4) {
        const float* row = lo + ((size_t)b * TT + t) * (2 * LH);
        float pn = 0.f, ps = 0.f;
#pragma unroll
        for (int c0 = 0; c0 < 256; c0 += 64) {
            float v = row[c0 + lane];
            pn += v * wn[c0 + lane];
            ps += v * wsp[c0 + lane];
        }
#pragma unroll
        for (int off = 32; off > 0; off >>= 1) {
            pn += __shfl_down(pn, off);
            ps += __shfl_down(ps, off);
        }
        if (lane == 0) { sn[t] = pn + bn[0]; ss[t] = ps + bsp[0]; }
    }
    __syncthreads();
    float vn = (tid < L) ? sn[tid] : -1e30f;
    float vs = (tid < L) ? ss[tid] : -1e30f;
    red[tid] = vn; __syncthreads();
    for (int s = 128; s > 0; s >>= 1) { if (tid < s) red[tid] = fmaxf(red[tid], red[tid + s]); __syncthreads(); }
    float mn = red[0]; __syncthreads();
    red[tid] = vs; __syncthreads();
    for (int s = 128; s > 0; s >>= 1) { if (tid < s) red[tid] = fmaxf(red[tid], red[tid + s]); __syncthreads(); }
    float ms = red[0]; __syncthreads();
    float en = (tid < L) ? __expf(vn - mn) : 0.f;
    float es = (tid < L) ? __expf(vs - ms) : 0.f;
    red[tid] = en; __syncthreads();
    for (int s = 128; s > 0; s >>= 1) { if (tid < s) red[tid] += red[tid + s]; __syncthreads(); }
    float dn = red[0]; __syncthreads();
    red[tid] = es; __syncthreads();
    for (int s = 128; s > 0; s >>= 1) { if (tid < s) red[tid] += red[tid + s]; __syncthreads(); }
    float dsum = red[0]; __syncthreads();
    if (tid < L) { sn[tid] = en / dn; ss[tid] = es / dsum; }
    __syncthreads();
    float an = 0.f, asv = 0.f;
    for (int t = 0; t < L; t++) {
        float v = lo[((size_t)b * TT + t) * (2 * LH) + tid];
        an += sn[t] * v;
        asv += ss[t] * v;
    }
    ctxn[b * (2 * LH) + tid] = an;
    ctxs[b * (2 * LH) + tid] = asv;
}

// ---------------------------------------------------------------- launch
extern "C" void kernel_launch(void* const* d_in, const int* in_sizes, int n_in,
                              void* d_out, int out_size, void* d_ws, size_t ws_size,
                              hipStream_t stream) {
    (void)in_sizes; (void)n_in; (void)out_size; (void)ws_size;
    const float* x_coords = (const float*)d_in[0];
    const float* temporal = (const float*)d_in[1];
    const float* node_emb = (const float*)d_in[2];
    const float* gat1_W   = (const float*)d_in[3];
    const float* gat1_as  = (const float*)d_in[4];
    const float* gat1_ad  = (const float*)d_in[5];
    const float* gat1_b   = (const float*)d_in[6];
    const float* gat2_W   = (const float*)d_in[7];
    const float* gat2_as  = (const float*)d_in[8];
    const float* gat2_ad  = (const float*)d_in[9];
    const float* gat2_b   = (const float*)d_in[10];
    const float* w_ih_f   = (const float*)d_in[11];
    const float* w_hh_f   = (const float*)d_in[12];
    const float* b_f      = (const float*)d_in[13];
    const float* w_ih_b   = (const float*)d_in[14];
    const float* w_hh_b   = (const float*)d_in[15];
    const float* b_b      = (const float*)d_in[16];
    const float* attn_n_w = (const float*)d_in[17];
    const float* attn_n_b = (const float*)d_in[18];
    const float* attn_s_w = (const float*)d_in[19];
    const float* attn_s_b = (const float*)d_in[20];
    const float* fc_n_W   = (const float*)d_in[21];
    const float* fc_n_b   = (const float*)d_in[22];
    const float* fc_s_W   = (const float*)d_in[23];
    const float* fc_s_b   = (const float*)d_in[24];
    const int*   edge_idx = (const int*)d_in[25];
    const int*   seq      = (const int*)d_in[26];
    const int*   lengths  = (const int*)d_in[27];

    char* ws = (char*)d_ws;
    size_t off = 0;
    auto alloc = [&](size_t bytes) -> char* {
        char* p = ws + off;
        off += (bytes + 255) & ~(size_t)255;
        return p;
    };
    int*   cnt      = (int*)alloc((size_t)N_NODES * 4);
    int*   rowstart = (int*)alloc((size_t)(N_NODES + 1) * 4);
    int*   cursor   = (int*)alloc((size_t)N_NODES * 4);
    int*   csr      = (int*)alloc((size_t)NE_TOT * 4);
    float* z2       = (float*)alloc((size_t)N_NODES * EMB * 4);
    float* lstm_o   = (float*)alloc((size_t)BB * TT * 2 * LH * 4);
    float* ctxn     = (float*)alloc((size_t)BB * 2 * LH * 4);
    float* ctxs     = (float*)alloc((size_t)BB * 2 * LH * 4);
    float* wT       = (float*)alloc((size_t)128 * 1024 * 4);
    float* bc       = (float*)alloc((size_t)1024 * 4);
    // reused region: GAT scratch first, then xg buffer (GAT scratch dead by then)
    float* nf  = (float*)(ws + off);
    float* w1p = nf + (size_t)N_NODES * KF;
    float* h1  = w1p + (size_t)KF * 256;
    float* as1 = h1 + (size_t)N_NODES * 256;
    float* ad1 = as1 + (size_t)N_NODES * 4;
    float* z1  = ad1 + (size_t)N_NODES * 4;
    float* h2  = z1 + (size_t)N_NODES * 256;
    float* as2 = h2 + (size_t)N_NODES * 128;
    float* ad2 = as2 + (size_t)N_NODES;
    float* xgc = (float*)(ws + off);               // [25600][1024], overlays nf..ad2

    // --- CSR build
    (void)hipMemsetAsync(cnt, 0, (size_t)N_NODES * 4, stream);
    k_count<<<(NE_TOT + 255) / 256, 256, 0, stream>>>(edge_idx, cnt);
    k_scan<<<1, 1024, 0, stream>>>(cnt, rowstart);
    (void)hipMemcpyAsync(cursor, rowstart, (size_t)N_NODES * 4, hipMemcpyDeviceToDevice, stream);
    k_scatter<<<(NE_TOT + 255) / 256, 256, 0, stream>>>(edge_idx, cursor, csr);

    // --- GAT layer 1
    k_build_nf<<<N_NODES, 192, 0, stream>>>(x_coords, temporal, node_emb, nf);
    k_build_w1p<<<KF, 256, 0, stream>>>(gat1_W, w1p);
    {
        dim3 g(2, (N_NODES + 127) / 128);
        k_gemm_f32<<<g, 256, 0, stream>>>(nf, w1p, h1, N_NODES, 256, KF, nullptr, nullptr);
    }
    k_attn_dots<HEADS, GH><<<(N_NODES * HEADS + 3) / 4, 256, 0, stream>>>(h1, gat1_as, gat1_ad, as1, ad1);
    k_gat_aggregate<HEADS, GH, true><<<N_NODES, 256, 0, stream>>>(h1, as1, ad1, rowstart, csr, gat1_b, z1);

    // --- GAT layer 2
    {
        dim3 g(1, (N_NODES + 127) / 128);
        k_gemm_f32<<<g, 256, 0, stream>>>(z1, gat2_W, h2, N_NODES, 128, 256, nullptr, nullptr);
    }
    k_attn_dots<1, EMB><<<(N_NODES + 3) / 4, 256, 0, stream>>>(h2, gat2_as, gat2_ad, as2, ad2);
    k_gat_aggregate<1, EMB, false><<<N_NODES, 128, 0, stream>>>(h2, as2, ad2, rowstart, csr, gat2_b, z2);

    // --- x-gate precompute, both directions in one GEMM (gather z2[seq] fused)
    k_build_wih<<<512, 256, 0, stream>>>(w_ih_f, w_ih_b, b_f, b_b, wT, bc);
    {
        dim3 g(8, (BB * TT) / 128);
        k_gemm_f32<<<g, 256, 0, stream>>>(z2, wT, xgc, BB * TT, 1024, 128, seq, bc);
    }

    // --- BiLSTM recurrence (W_hh pinned in VGPRs via one opaque asm block)
    k_lstm<<<256, 1024, 0, stream>>>(xgc, w_hh_f, w_hh_b, lengths, lstm_o);

    // --- attention pooling
    k_attnpool<<<BB, 256, 0, stream>>>(lstm_o, lengths, attn_n_w, attn_n_b, attn_s_w, attn_s_b, ctxn, ctxs);

    // --- output heads
    float* out_node = (float*)d_out;
    float* out_sp   = out_node + (size_t)BB * N_NODES;
    {
        dim3 g((N_NODES + 127) / 128, 1);
        k_gemm_f32<<<g, 256, 0, stream>>>(ctxn, fc_n_W, out_node, BB, N_NODES, 256, nullptr, fc_n_b);
    }
    {
        dim3 g(1, 1);
        k_gemm_f32<<<g, 256, 0, stream>>>(ctxs, fc_s_W, out_sp, BB, NSP, 256, nullptr, fc_s_b);
    }
}